// Round 4
// baseline (528.198 us; speedup 1.0000x reference)
//
#include <hip/hip_runtime.h>
#include <hip/hip_bf16.h>

typedef __attribute__((ext_vector_type(8))) short short8;
typedef __attribute__((ext_vector_type(4))) float f32x4;

#define TDIM 512
#define FDIM 1024

__device__ __forceinline__ float sigm(float x)  { return 1.0f / (1.0f + __expf(-x)); }
__device__ __forceinline__ float tanh_f(float x){ return 1.0f - 2.0f / (__expf(2.0f * x) + 1.0f); }
__device__ __forceinline__ float  bf2f(ushort u) { return __uint_as_float(((unsigned)u) << 16); }
__device__ __forceinline__ ushort f2bf(float f)  { return __bfloat16_as_ushort(__float2bfloat16(f)); }
// swizzled index into a [rows][128] bf16 LDS tile (byte ^= (row&7)<<4  =>  elem ^= (row&7)<<3)
__device__ __forceinline__ int hidx(int row, int d) { return row * 128 + (d ^ ((row & 7) << 3)); }

// ---------------------------------------------------------------------------
// prep: blocks 0..127: fc1_w fp32 -> bf16 (same [d][f] layout)
//       blocks 128..143: emb_w1 fp32 -> bf16 (native [d1][k], k-contiguous)
//       blocks 144..207: w2t fp32 transpose (for final_k)
__global__ __launch_bounds__(256) void prep_k(const float* __restrict__ fc1_w,
                                              const float* __restrict__ w1,
                                              const float* __restrict__ w2,
                                              ushort* __restrict__ wb16,
                                              ushort* __restrict__ w1b,
                                              float* __restrict__ w2t) {
    int blk = blockIdx.x, tid = threadIdx.x;
    if (blk < 128) {
        int idx = blk * 256 + tid;                      // 0..32767 float4s
        float4 v = reinterpret_cast<const float4*>(fc1_w)[idx];
        ushort4 o = { f2bf(v.x), f2bf(v.y), f2bf(v.z), f2bf(v.w) };
        reinterpret_cast<ushort4*>(wb16)[idx] = o;
    } else if (blk < 144) {
        int idx = (blk - 128) * 256 + tid;              // 0..4095 float4s
        float4 v = reinterpret_cast<const float4*>(w1)[idx];
        ushort4 o = { f2bf(v.x), f2bf(v.y), f2bf(v.z), f2bf(v.w) };
        reinterpret_cast<ushort4*>(w1b)[idx] = o;
    } else {
        int idx = (blk - 144) * 256 + tid;              // 0..16383
        int k = idx >> 7, d = idx & 127;
        w2t[idx] = w2[d * 128 + k];
    }
}

// ---------------------------------------------------------------------------
// fused: MFMA fc1 (32t x 128d, K=1024, prefetch-pipelined, no LDS in K-loop)
//        -> biLSTM(H=1) with y accumulated in bf16 swizzled [row][k] LDS
//        -> emb1 via MFMA (y @ w1^T), leaky, row-sum -> partials.
// Block: 256 threads = 4 waves (2x2; wave tile 16t x 64d). Grid: 1024 (4/CU).
__global__ __launch_bounds__(256, 4) void fused_k(
    const float* __restrict__ x,
    const ushort* __restrict__ wb16, const float* __restrict__ fc1_b,
    const float* __restrict__ wih_f, const float* __restrict__ whh_f,
    const float* __restrict__ bih_f, const float* __restrict__ bhh_f,
    const float* __restrict__ wih_b, const float* __restrict__ whh_b,
    const float* __restrict__ bih_b, const float* __restrict__ bhh_b,
    const float* __restrict__ lout_w, const float* __restrict__ lout_b,
    const ushort* __restrict__ w1b, const float* __restrict__ emb_b1,
    float* __restrict__ partials)
{
    __shared__ __align__(16) ushort h16[32 * 128];   // 8 KB: fc1 out (bf16, swizzled); later psum (fp32, 4 KB)
    __shared__ __align__(16) ushort y16[32 * 128];   // 8 KB: y (bf16, swizzled [row][k] = emb A-layout)

    int tid = threadIdx.x;
    int blk = blockIdx.x;
    int b  = blk >> 4;
    int t0 = (blk & 15) * 32;

    int lane = tid & 63;
    int wid  = tid >> 6;
    int wr = wid >> 1, wc = wid & 1;
    int l15 = lane & 15, g = lane >> 4;

    // ---- Phase 1: fc1 GEMM, depth-2 A-prefetch, depth-1 B-prefetch ----
    const float*  xl = x + (size_t)b * (FDIM * TDIM) + (t0 + wr * 16 + l15);
    const ushort* wl = wb16 + (size_t)(wc * 64 + l15) * FDIM + g * 8;

    float  av[2][8];
    short8 bq[2][4];
#pragma unroll
    for (int j = 0; j < 8; ++j) av[0][j] = xl[(size_t)(g * 8 + j) * TDIM];
#pragma unroll
    for (int j = 0; j < 8; ++j) av[1][j] = xl[(size_t)(32 + g * 8 + j) * TDIM];
#pragma unroll
    for (int ni = 0; ni < 4; ++ni)
        bq[0][ni] = *reinterpret_cast<const short8*>(wl + (size_t)ni * 16 * FDIM);

    f32x4 acc[4] = {f32x4{0,0,0,0}, f32x4{0,0,0,0}, f32x4{0,0,0,0}, f32x4{0,0,0,0}};

    for (int it = 0; it < 32; ++it) {
        int k0 = it * 32;
        int cur = it & 1;
        short8 a;
#pragma unroll
        for (int j = 0; j < 8; ++j) a[j] = (short)f2bf(av[cur][j]);
        int kpfA = (k0 + 64) & 1023;                 // wrapped: legal addr, last 2 unused
#pragma unroll
        for (int j = 0; j < 8; ++j)
            av[cur][j] = xl[(size_t)(kpfA + g * 8 + j) * TDIM];
        int kpfB = (k0 + 32) & 1023;
#pragma unroll
        for (int ni = 0; ni < 4; ++ni)
            bq[cur ^ 1][ni] = *reinterpret_cast<const short8*>(wl + kpfB + (size_t)ni * 16 * FDIM);
#pragma unroll
        for (int ni = 0; ni < 4; ++ni)
            acc[ni] = __builtin_amdgcn_mfma_f32_16x16x32_bf16(a, bq[cur][ni], acc[ni], 0, 0, 0);
    }

    // Epilogue: C layout col=lane&15, row=(lane>>4)*4+reg -> bf16 swizzled LDS
#pragma unroll
    for (int ni = 0; ni < 4; ++ni) {
        int col = wc * 64 + ni * 16 + l15;
        float bias = fc1_b[col];
#pragma unroll
        for (int r = 0; r < 4; ++r) {
            int row = wr * 16 + g * 4 + r;
            h16[hidx(row, col)] = f2bf(acc[ni][r] + bias);
        }
    }

    // y init = lout_b (swizzle-invariant: uniform value)
    {
        ushort lbu = f2bf(lout_b[0]);
        ushort4 lv = { lbu, lbu, lbu, lbu };
#pragma unroll
        for (int i = 0; i < 4; ++i)
            reinterpret_cast<ushort4*>(y16)[i * 256 + tid] = lv;
    }
    __syncthreads();

    // ---- Phase 2: biLSTM, thread=(row,dir), 64 threads (wave 0), H=1 ----
    if (tid < 64) {
        int row = tid >> 1, dir = tid & 1;
        const float* wih = dir ? wih_b : wih_f;
        const float* whh = dir ? whh_b : whh_f;
        const float* bi  = dir ? bih_b : bih_f;
        const float* bh  = dir ? bhh_b : bhh_f;
        float wi0 = wih[0], wi1 = wih[1], wi2 = wih[2], wi3 = wih[3];
        float wh0 = whh[0], wh1 = whh[1], wh2 = whh[2], wh3 = whh[3];
        float c0 = bi[0] + bh[0], c1 = bi[1] + bh[1], c2 = bi[2] + bh[2], c3 = bi[3] + bh[3];
        float wsel = lout_w[dir];
        float hh = 0.f, cc = 0.f;
        for (int s = 0; s < 128; ++s) {
            int d = dir ? (127 - s) : s;
            float xv = bf2f(h16[hidx(row, d)]);
            float gi = fmaf(wi0, xv, fmaf(wh0, hh, c0));
            float gf = fmaf(wi1, xv, fmaf(wh1, hh, c1));
            float gg = fmaf(wi2, xv, fmaf(wh2, hh, c2));
            float go = fmaf(wi3, xv, fmaf(wh3, hh, c3));
            cc = sigm(gf) * cc + sigm(gi) * tanh_f(gg);
            hh = sigm(go) * tanh_f(cc);
            // fwd touches d=s, bwd d=127-s: distinct cells per step; same-wave
            // lockstep orders the cross-step RMWs to a shared cell -> race-free
            int yi = hidx(row, d);
            y16[yi] = f2bf(bf2f(y16[yi]) + wsel * hh);
        }
    }
    __syncthreads();

    // ---- Phase 3: emb1 = leaky(y @ w1^T + b1) via MFMA, then row-sum ----
    f32x4 accE[4] = {f32x4{0,0,0,0}, f32x4{0,0,0,0}, f32x4{0,0,0,0}, f32x4{0,0,0,0}};
    {
        int ro = wr * 16 + l15;                          // A-frag row (y row)
        int sw = (ro & 7) << 3;
        const ushort* w1p = w1b + (size_t)(wc * 64 + l15) * 128 + g * 8;
#pragma unroll
        for (int k0 = 0; k0 < 128; k0 += 32) {
            short8 ya = *reinterpret_cast<const short8*>(&y16[ro * 128 + ((k0 + g * 8) ^ sw)]);
#pragma unroll
            for (int ni = 0; ni < 4; ++ni) {
                short8 wf = *reinterpret_cast<const short8*>(w1p + k0 + (size_t)ni * 16 * 128);
                accE[ni] = __builtin_amdgcn_mfma_f32_16x16x32_bf16(ya, wf, accE[ni], 0, 0, 0);
            }
        }
    }
    float* psum = reinterpret_cast<float*>(h16);         // h dead; 8x128 fp32 = 4 KB
#pragma unroll
    for (int ni = 0; ni < 4; ++ni) {
        int d1 = wc * 64 + ni * 16 + l15;
        float b1v = emb_b1[d1];
        float s = 0.f;
#pragma unroll
        for (int j = 0; j < 4; ++j) {
            float e = accE[ni][j] + b1v;
            s += (e >= 0.f) ? e : 0.2f * e;
        }
        psum[(wr * 4 + g) * 128 + d1] = s;
    }
    __syncthreads();
    if (tid < 128) {
        float s = 0.f;
#pragma unroll
        for (int rg = 0; rg < 8; ++rg) s += psum[rg * 128 + tid];
        partials[(size_t)blk * 128 + tid] = s;
    }
}

// ---------------------------------------------------------------------------
// final: per-batch reduce of 16 partials, /T, then @ emb_w2^T + b2.
__global__ __launch_bounds__(128) void final_k(const float* __restrict__ partials,
                                               const float* __restrict__ w2t,
                                               const float* __restrict__ emb_b2,
                                               float* __restrict__ out) {
    __shared__ float S[128];
    int b = blockIdx.x, tid = threadIdx.x;
    float s = 0.f;
#pragma unroll
    for (int p = 0; p < 16; ++p) s += partials[(size_t)(b * 16 + p) * 128 + tid];
    S[tid] = s * (1.0f / 512.0f);
    __syncthreads();
    float acc = emb_b2[tid];
    for (int k = 0; k < 128; ++k) acc = fmaf(S[k], w2t[k * 128 + tid], acc);
    out[b * 128 + tid] = acc;
}

// ---------------------------------------------------------------------------
extern "C" void kernel_launch(void* const* d_in, const int* in_sizes, int n_in,
                              void* d_out, int out_size, void* d_ws, size_t ws_size,
                              hipStream_t stream) {
    const float* x      = (const float*)d_in[0];
    const float* fc1_w  = (const float*)d_in[1];
    const float* fc1_b  = (const float*)d_in[2];
    const float* wih_f  = (const float*)d_in[3];
    const float* whh_f  = (const float*)d_in[4];
    const float* bih_f  = (const float*)d_in[5];
    const float* bhh_f  = (const float*)d_in[6];
    const float* wih_b  = (const float*)d_in[7];
    const float* whh_b  = (const float*)d_in[8];
    const float* bih_b  = (const float*)d_in[9];
    const float* bhh_b  = (const float*)d_in[10];
    const float* lout_w = (const float*)d_in[11];
    const float* lout_b = (const float*)d_in[12];
    const float* emb_w1 = (const float*)d_in[13];
    const float* emb_b1 = (const float*)d_in[14];
    const float* emb_w2 = (const float*)d_in[15];
    const float* emb_b2 = (const float*)d_in[16];
    float* out = (float*)d_out;

    float*  partials = (float*)d_ws;               // 1024*128 fp32 = 512 KB
    float*  w2t  = partials + 1024 * 128;          // 16384 fp32 = 64 KB
    ushort* wb16 = (ushort*)(w2t + 16384);         // 131072 bf16 = 256 KB
    ushort* w1b  = wb16 + 131072;                  // 16384 bf16 = 32 KB

    prep_k<<<208, 256, 0, stream>>>(fc1_w, emb_w1, emb_w2, wb16, w1b, w2t);
    fused_k<<<1024, 256, 0, stream>>>(x, wb16, fc1_b,
                                      wih_f, whh_f, bih_f, bhh_f,
                                      wih_b, whh_b, bih_b, bhh_b,
                                      lout_w, lout_b, w1b, emb_b1, partials);
    final_k<<<64, 128, 0, stream>>>(partials, w2t, emb_b2, out);
}

// Round 6
// 314.048 us; speedup vs baseline: 1.6819x; 1.6819x over previous
//
#include <hip/hip_runtime.h>
#include <hip/hip_bf16.h>

typedef __attribute__((ext_vector_type(8))) short short8;
typedef __attribute__((ext_vector_type(4))) float f32x4;

#define TDIM 512
#define FDIM 1024

__device__ __forceinline__ float sigm(float x)  { return 1.0f / (1.0f + __expf(-x)); }
__device__ __forceinline__ float tanh_f(float x){ return 1.0f - 2.0f / (__expf(2.0f * x) + 1.0f); }
__device__ __forceinline__ float  bf2f(ushort u) { return __uint_as_float(((unsigned)u) << 16); }
__device__ __forceinline__ ushort f2bf(float f)  { return __bfloat16_as_ushort(__float2bfloat16(f)); }
// swizzled index into a [rows][128] bf16 LDS tile (byte ^= (row&7)<<4  =>  elem ^= (row&7)<<3)
__device__ __forceinline__ int hidx(int row, int d) { return row * 128 + (d ^ ((row & 7) << 3)); }

// ---------------------------------------------------------------------------
// prep: blocks 0..127: fc1_w fp32 -> bf16 (same [d][f] layout)
//       blocks 128..143: emb_w1 fp32 -> bf16 (native [d1][k], k-contiguous)
//       blocks 144..207: w2t fp32 transpose (for final_k)
__global__ __launch_bounds__(256) void prep_k(const float* __restrict__ fc1_w,
                                              const float* __restrict__ w1,
                                              const float* __restrict__ w2,
                                              ushort* __restrict__ wb16,
                                              ushort* __restrict__ w1b,
                                              float* __restrict__ w2t) {
    int blk = blockIdx.x, tid = threadIdx.x;
    if (blk < 128) {
        int idx = blk * 256 + tid;                      // 0..32767 float4s
        float4 v = reinterpret_cast<const float4*>(fc1_w)[idx];
        ushort4 o = { f2bf(v.x), f2bf(v.y), f2bf(v.z), f2bf(v.w) };
        reinterpret_cast<ushort4*>(wb16)[idx] = o;
    } else if (blk < 144) {
        int idx = (blk - 128) * 256 + tid;              // 0..4095 float4s
        float4 v = reinterpret_cast<const float4*>(w1)[idx];
        ushort4 o = { f2bf(v.x), f2bf(v.y), f2bf(v.z), f2bf(v.w) };
        reinterpret_cast<ushort4*>(w1b)[idx] = o;
    } else {
        int idx = (blk - 144) * 256 + tid;              // 0..16383
        int k = idx >> 7, d = idx & 127;
        w2t[idx] = w2[d * 128 + k];
    }
}

// ---------------------------------------------------------------------------
// fused: MFMA fc1 (32t x 128d, K=1024, depth-2 register pipeline with STATIC
//        indexing only — named buffers, rule #20) -> biLSTM(H=1) -> y (bf16
//        swizzled LDS) -> emb1 via MFMA -> leaky -> row-sum -> partials.
// Block: 256 threads = 4 waves (2x2; wave tile 16t x 64d). Grid: 1024 (4/CU).
__global__ __launch_bounds__(256, 4) void fused_k(
    const float* __restrict__ x,
    const ushort* __restrict__ wb16, const float* __restrict__ fc1_b,
    const float* __restrict__ wih_f, const float* __restrict__ whh_f,
    const float* __restrict__ bih_f, const float* __restrict__ bhh_f,
    const float* __restrict__ wih_b, const float* __restrict__ whh_b,
    const float* __restrict__ bih_b, const float* __restrict__ bhh_b,
    const float* __restrict__ lout_w, const float* __restrict__ lout_b,
    const ushort* __restrict__ w1b, const float* __restrict__ emb_b1,
    float* __restrict__ partials)
{
    __shared__ __align__(16) ushort h16[32 * 128];   // 8 KB: fc1 out (bf16, swizzled); later psum (fp32)
    __shared__ __align__(16) ushort y16[32 * 128];   // 8 KB: y (bf16, swizzled [row][k] = emb A-layout)

    int tid = threadIdx.x;
    int blk = blockIdx.x;
    int b  = blk >> 4;
    int t0 = (blk & 15) * 32;

    int lane = tid & 63;
    int wid  = tid >> 6;
    int wr = wid >> 1, wc = wid & 1;
    int l15 = lane & 15, g = lane >> 4;

    // ---- Phase 1: fc1 GEMM. Named double-buffers, all indices static. ----
    const float*  xl = x + (size_t)b * (FDIM * TDIM) + (t0 + wr * 16 + l15);
    const ushort* wl = wb16 + (size_t)(wc * 64 + l15) * FDIM + g * 8;

    float  avA[8], avB[8];
    short8 bqA[4], bqB[4];
#pragma unroll
    for (int j = 0; j < 8; ++j) avA[j] = xl[(size_t)(g * 8 + j) * TDIM];          // k=0
#pragma unroll
    for (int j = 0; j < 8; ++j) avB[j] = xl[(size_t)(32 + g * 8 + j) * TDIM];     // k=32
#pragma unroll
    for (int ni = 0; ni < 4; ++ni)
        bqA[ni] = *reinterpret_cast<const short8*>(wl + (size_t)ni * 16 * FDIM);  // k=0

    f32x4 acc[4] = {f32x4{0,0,0,0}, f32x4{0,0,0,0}, f32x4{0,0,0,0}, f32x4{0,0,0,0}};

    for (int it = 0; it < 16; ++it) {
        const int k0 = it * 64;
        // --- sub-step 0: compute k0 from avA/bqA; prefetch avA<-k0+64, bqB<-k0+32
        {
            short8 a;
#pragma unroll
            for (int j = 0; j < 8; ++j) a[j] = (short)f2bf(avA[j]);
            const int kA = (k0 + 64) & 1023;          // wrapped: legal, last iters' garbage unused
#pragma unroll
            for (int j = 0; j < 8; ++j) avA[j] = xl[(size_t)(kA + g * 8 + j) * TDIM];
            const int kB = k0 + 32;                   // <= 992, in-bounds
#pragma unroll
            for (int ni = 0; ni < 4; ++ni)
                bqB[ni] = *reinterpret_cast<const short8*>(wl + kB + (size_t)ni * 16 * FDIM);
#pragma unroll
            for (int ni = 0; ni < 4; ++ni)
                acc[ni] = __builtin_amdgcn_mfma_f32_16x16x32_bf16(a, bqA[ni], acc[ni], 0, 0, 0);
        }
        // --- sub-step 1: compute k0+32 from avB/bqB; prefetch avB<-k0+96, bqA<-k0+64
        {
            short8 a;
#pragma unroll
            for (int j = 0; j < 8; ++j) a[j] = (short)f2bf(avB[j]);
            const int kA = (k0 + 96) & 1023;
#pragma unroll
            for (int j = 0; j < 8; ++j) avB[j] = xl[(size_t)(kA + g * 8 + j) * TDIM];
            const int kB = (k0 + 64) & 1023;
#pragma unroll
            for (int ni = 0; ni < 4; ++ni)
                bqA[ni] = *reinterpret_cast<const short8*>(wl + kB + (size_t)ni * 16 * FDIM);
#pragma unroll
            for (int ni = 0; ni < 4; ++ni)
                acc[ni] = __builtin_amdgcn_mfma_f32_16x16x32_bf16(a, bqB[ni], acc[ni], 0, 0, 0);
        }
    }

    // Epilogue: C layout col=lane&15, row=(lane>>4)*4+reg -> bf16 swizzled LDS
#pragma unroll
    for (int ni = 0; ni < 4; ++ni) {
        int col = wc * 64 + ni * 16 + l15;
        float bias = fc1_b[col];
#pragma unroll
        for (int r = 0; r < 4; ++r) {
            int row = wr * 16 + g * 4 + r;
            h16[hidx(row, col)] = f2bf(acc[ni][r] + bias);
        }
    }

    // y init = lout_b (swizzle-invariant: uniform value)
    {
        ushort lbu = f2bf(lout_b[0]);
        ushort4 lv = { lbu, lbu, lbu, lbu };
#pragma unroll
        for (int i = 0; i < 4; ++i)
            reinterpret_cast<ushort4*>(y16)[i * 256 + tid] = lv;
    }
    __syncthreads();

    // ---- Phase 2: biLSTM, thread=(row,dir), 64 threads (wave 0), H=1 ----
    if (tid < 64) {
        int row = tid >> 1, dir = tid & 1;
        const float* wih = dir ? wih_b : wih_f;
        const float* whh = dir ? whh_b : whh_f;
        const float* bi  = dir ? bih_b : bih_f;
        const float* bh  = dir ? bhh_b : bhh_f;
        float wi0 = wih[0], wi1 = wih[1], wi2 = wih[2], wi3 = wih[3];
        float wh0 = whh[0], wh1 = whh[1], wh2 = whh[2], wh3 = whh[3];
        float c0 = bi[0] + bh[0], c1 = bi[1] + bh[1], c2 = bi[2] + bh[2], c3 = bi[3] + bh[3];
        float wsel = lout_w[dir];
        float hh = 0.f, cc = 0.f;
        for (int s = 0; s < 128; ++s) {
            int d = dir ? (127 - s) : s;
            float xv = bf2f(h16[hidx(row, d)]);
            float gi = fmaf(wi0, xv, fmaf(wh0, hh, c0));
            float gf = fmaf(wi1, xv, fmaf(wh1, hh, c1));
            float gg = fmaf(wi2, xv, fmaf(wh2, hh, c2));
            float go = fmaf(wi3, xv, fmaf(wh3, hh, c3));
            cc = sigm(gf) * cc + sigm(gi) * tanh_f(gg);
            hh = sigm(go) * tanh_f(cc);
            // fwd touches d=s, bwd d=127-s: distinct cells per step; same-wave
            // lockstep orders the cross-step RMWs to a shared cell -> race-free
            int yi = hidx(row, d);
            y16[yi] = f2bf(bf2f(y16[yi]) + wsel * hh);
        }
    }
    __syncthreads();

    // ---- Phase 3: emb1 = leaky(y @ w1^T + b1) via MFMA, then row-sum ----
    f32x4 accE[4] = {f32x4{0,0,0,0}, f32x4{0,0,0,0}, f32x4{0,0,0,0}, f32x4{0,0,0,0}};
    {
        int ro = wr * 16 + l15;                          // A-frag row (y row)
        int sw = (ro & 7) << 3;
        const ushort* w1p = w1b + (size_t)(wc * 64 + l15) * 128 + g * 8;
#pragma unroll
        for (int k0 = 0; k0 < 128; k0 += 32) {
            short8 ya = *reinterpret_cast<const short8*>(&y16[ro * 128 + ((k0 + g * 8) ^ sw)]);
#pragma unroll
            for (int ni = 0; ni < 4; ++ni) {
                short8 wf = *reinterpret_cast<const short8*>(w1p + k0 + (size_t)ni * 16 * 128);
                accE[ni] = __builtin_amdgcn_mfma_f32_16x16x32_bf16(ya, wf, accE[ni], 0, 0, 0);
            }
        }
    }
    float* psum = reinterpret_cast<float*>(h16);         // h dead; 8x128 fp32 = 4 KB
#pragma unroll
    for (int ni = 0; ni < 4; ++ni) {
        int d1 = wc * 64 + ni * 16 + l15;
        float b1v = emb_b1[d1];
        float s = 0.f;
#pragma unroll
        for (int j = 0; j < 4; ++j) {
            float e = accE[ni][j] + b1v;
            s += (e >= 0.f) ? e : 0.2f * e;
        }
        psum[(wr * 4 + g) * 128 + d1] = s;
    }
    __syncthreads();
    if (tid < 128) {
        float s = 0.f;
#pragma unroll
        for (int rg = 0; rg < 8; ++rg) s += psum[rg * 128 + tid];
        partials[(size_t)blk * 128 + tid] = s;
    }
}

// ---------------------------------------------------------------------------
// final: per-batch reduce of 16 partials, /T, then @ emb_w2^T + b2.
__global__ __launch_bounds__(128) void final_k(const float* __restrict__ partials,
                                               const float* __restrict__ w2t,
                                               const float* __restrict__ emb_b2,
                                               float* __restrict__ out) {
    __shared__ float S[128];
    int b = blockIdx.x, tid = threadIdx.x;
    float s = 0.f;
#pragma unroll
    for (int p = 0; p < 16; ++p) s += partials[(size_t)(b * 16 + p) * 128 + tid];
    S[tid] = s * (1.0f / 512.0f);
    __syncthreads();
    float acc = emb_b2[tid];
    for (int k = 0; k < 128; ++k) acc = fmaf(S[k], w2t[k * 128 + tid], acc);
    out[b * 128 + tid] = acc;
}

// ---------------------------------------------------------------------------
extern "C" void kernel_launch(void* const* d_in, const int* in_sizes, int n_in,
                              void* d_out, int out_size, void* d_ws, size_t ws_size,
                              hipStream_t stream) {
    const float* x      = (const float*)d_in[0];
    const float* fc1_w  = (const float*)d_in[1];
    const float* fc1_b  = (const float*)d_in[2];
    const float* wih_f  = (const float*)d_in[3];
    const float* whh_f  = (const float*)d_in[4];
    const float* bih_f  = (const float*)d_in[5];
    const float* bhh_f  = (const float*)d_in[6];
    const float* wih_b  = (const float*)d_in[7];
    const float* whh_b  = (const float*)d_in[8];
    const float* bih_b  = (const float*)d_in[9];
    const float* bhh_b  = (const float*)d_in[10];
    const float* lout_w = (const float*)d_in[11];
    const float* lout_b = (const float*)d_in[12];
    const float* emb_w1 = (const float*)d_in[13];
    const float* emb_b1 = (const float*)d_in[14];
    const float* emb_w2 = (const float*)d_in[15];
    const float* emb_b2 = (const float*)d_in[16];
    float* out = (float*)d_out;

    float*  partials = (float*)d_ws;               // 1024*128 fp32 = 512 KB
    float*  w2t  = partials + 1024 * 128;          // 16384 fp32 = 64 KB
    ushort* wb16 = (ushort*)(w2t + 16384);         // 131072 bf16 = 256 KB
    ushort* w1b  = wb16 + 131072;                  // 16384 bf16 = 32 KB

    prep_k<<<208, 256, 0, stream>>>(fc1_w, emb_w1, emb_w2, wb16, w1b, w2t);
    fused_k<<<1024, 256, 0, stream>>>(x, wb16, fc1_b,
                                      wih_f, whh_f, bih_f, bhh_f,
                                      wih_b, whh_b, bih_b, bhh_b,
                                      lout_w, lout_b, w1b, emb_b1, partials);
    final_k<<<64, 128, 0, stream>>>(partials, w2t, emb_b2, out);
}

// Round 7
// 271.218 us; speedup vs baseline: 1.9475x; 1.1579x over previous
//
#include <hip/hip_runtime.h>
#include <hip/hip_bf16.h>

typedef __attribute__((ext_vector_type(8))) short short8;
typedef __attribute__((ext_vector_type(4))) float f32x4;

#define TDIM 512
#define FDIM 1024

__device__ __forceinline__ float sigm(float x)  { return 1.0f / (1.0f + __expf(-x)); }
__device__ __forceinline__ float tanh_f(float x){ return 1.0f - 2.0f / (__expf(2.0f * x) + 1.0f); }
__device__ __forceinline__ float  bf2f(ushort u) { return __uint_as_float(((unsigned)u) << 16); }
__device__ __forceinline__ ushort f2bf(float f)  { return __bfloat16_as_ushort(__float2bfloat16(f)); }
// swizzled index into a [rows][128] bf16 LDS tile (byte ^= (row&7)<<4 => elem ^= (row&7)<<3)
__device__ __forceinline__ int hidx(int row, int d) { return row * 128 + (d ^ ((row & 7) << 3)); }

// global -> LDS direct copy, 16B per lane; LDS dest must be wave-uniform base.
__device__ __forceinline__ void gl_lds16(const void* g, void* l) {
    __builtin_amdgcn_global_load_lds(
        (const __attribute__((address_space(1))) void*)g,
        (__attribute__((address_space(3))) void*)l, 16, 0, 0);
}

// ---------------------------------------------------------------------------
// prep: blocks 0..127: fc1_w fp32 -> bf16 (same [d][f] layout)
//       blocks 128..143: emb_w1 fp32 -> bf16 (native [d1][k], k-contiguous)
//       blocks 144..207: w2t fp32 transpose (for final_k)
__global__ __launch_bounds__(256) void prep_k(const float* __restrict__ fc1_w,
                                              const float* __restrict__ w1,
                                              const float* __restrict__ w2,
                                              ushort* __restrict__ wb16,
                                              ushort* __restrict__ w1b,
                                              float* __restrict__ w2t) {
    int blk = blockIdx.x, tid = threadIdx.x;
    if (blk < 128) {
        int idx = blk * 256 + tid;
        float4 v = reinterpret_cast<const float4*>(fc1_w)[idx];
        ushort4 o = { f2bf(v.x), f2bf(v.y), f2bf(v.z), f2bf(v.w) };
        reinterpret_cast<ushort4*>(wb16)[idx] = o;
    } else if (blk < 144) {
        int idx = (blk - 128) * 256 + tid;
        float4 v = reinterpret_cast<const float4*>(w1)[idx];
        ushort4 o = { f2bf(v.x), f2bf(v.y), f2bf(v.z), f2bf(v.w) };
        reinterpret_cast<ushort4*>(w1b)[idx] = o;
    } else {
        int idx = (blk - 144) * 256 + tid;
        int k = idx >> 7, d = idx & 127;
        w2t[idx] = w2[d * 128 + k];
    }
}

// ---------------------------------------------------------------------------
// fused: m97-style LDS-staged MFMA fc1 (BM=64t x BN=128d, BK=64, double-buffer
//        via global_load_lds, pre-swizzled sources) -> biLSTM(H=1) -> y (bf16
//        swizzled LDS) -> emb1 via MFMA -> leaky -> row-sum -> partials.
// Block: 256 threads = 4 waves (2x2: wr=t-half(32), wc=d-half(64)). Grid 512 (2/CU).
// LDS pool 64 KB: GEMM {As[2][64k][64t] fp32 32K | Bs[2][128d][64k] bf16 32K},
// phases alias {h16 16K @0 | y16 16K @32K | psum 8K @0}.
__global__ __launch_bounds__(256, 2) void fused_k(
    const float* __restrict__ x,
    const ushort* __restrict__ wb16, const float* __restrict__ fc1_b,
    const float* __restrict__ wih_f, const float* __restrict__ whh_f,
    const float* __restrict__ bih_f, const float* __restrict__ bhh_f,
    const float* __restrict__ wih_b, const float* __restrict__ whh_b,
    const float* __restrict__ bih_b, const float* __restrict__ bhh_b,
    const float* __restrict__ lout_w, const float* __restrict__ lout_b,
    const ushort* __restrict__ w1b, const float* __restrict__ emb_b1,
    float* __restrict__ partials)
{
    __shared__ __align__(16) char smem[65536];

    int tid = threadIdx.x;
    int blk = blockIdx.x;
    int b  = blk >> 3;
    int t0 = (blk & 7) * 64;

    const int lane = tid & 63;
    const int wid  = tid >> 6;
    const int wr = wid >> 1, wc = wid & 1;
    const int l15 = lane & 15, g = lane >> 4;

    const float* xA = x + (size_t)b * (FDIM * TDIM) + t0;

    // ---- Phase 1: fc1 GEMM, 2-phase double-buffered global_load_lds ----
    // A LDS layout [k][64t] fp32, source pre-swizzled: stored[k][slot16B s] =
    //   logical t-slot (s ^ (((k>>3)&1)<<2))  -> 2-way-free frag reads.
    // B LDS layout [d][64k] bf16, stored[d][slot16B s] = logical k-slot (s ^ (d&7)).
    auto STAGE = [&](int buf, int k0) {
#pragma unroll
        for (int q = 0; q < 4; ++q) {                     // A: 16KB, inst i = 1KB
            int i = wid * 4 + q;
            int k = i * 4 + (lane >> 4);                  // 0..63
            int tslot = l15 ^ (((k >> 3) & 1) << 2);
            gl_lds16(xA + (size_t)(k0 + k) * TDIM + tslot * 4,
                     smem + (buf << 14) + i * 1024);
        }
#pragma unroll
        for (int q = 0; q < 4; ++q) {                     // B: 16KB
            int i = wid * 4 + q;
            int d = i * 8 + (lane >> 3);                  // 0..127
            int kslot = (lane & 7) ^ ((lane >> 3) & 7);
            gl_lds16(wb16 + (size_t)d * FDIM + k0 + kslot * 8,
                     smem + 32768 + (buf << 14) + i * 1024);
        }
    };

    f32x4 acc[2][4];
#pragma unroll
    for (int mi = 0; mi < 2; ++mi)
#pragma unroll
        for (int ni = 0; ni < 4; ++ni) acc[mi][ni] = f32x4{0, 0, 0, 0};

    int buf = 0;
    STAGE(0, 0);
    __syncthreads();                                      // buf0 staged

    for (int s = 0; s < 16; ++s) {
        if (s < 15) STAGE(buf ^ 1, (s + 1) * 64);         // queue next tile (VMEM)
        const char* Ab = smem + (buf << 14);
        const char* Bb = smem + 32768 + (buf << 14);
#pragma unroll
        for (int ks = 0; ks < 2; ++ks) {
            short8 a[2];
#pragma unroll
            for (int mi = 0; mi < 2; ++mi) {
                int t_loc = wr * 32 + mi * 16 + l15;
                int tbyte = (t_loc * 4) ^ ((g & 1) << 6); // matches staging swizzle
#pragma unroll
                for (int j = 0; j < 8; ++j) {
                    float v = *(const float*)(Ab + (ks * 32 + g * 8 + j) * 256 + tbyte);
                    a[mi][j] = (short)f2bf(v);
                }
            }
#pragma unroll
            for (int ni = 0; ni < 4; ++ni) {
                int d_loc = wc * 64 + ni * 16 + l15;
                short8 bfr = *(const short8*)(Bb + d_loc * 128 +
                                              ((((ks << 2) + g) ^ (l15 & 7)) << 4));
                acc[0][ni] = __builtin_amdgcn_mfma_f32_16x16x32_bf16(a[0], bfr, acc[0][ni], 0, 0, 0);
                acc[1][ni] = __builtin_amdgcn_mfma_f32_16x16x32_bf16(a[1], bfr, acc[1][ni], 0, 0, 0);
            }
        }
        __syncthreads();                                  // next buf staged + reads drained
        buf ^= 1;
    }

    // ---- Epilogue: h = acc + bias -> h16 bf16 swizzled [64][128] ----
    ushort* h16 = (ushort*)smem;                          // 16 KB (As buf0, dead)
    ushort* y16 = (ushort*)(smem + 32768);                // 16 KB (Bs buf0, dead)
#pragma unroll
    for (int mi = 0; mi < 2; ++mi)
#pragma unroll
        for (int ni = 0; ni < 4; ++ni) {
            int col = wc * 64 + ni * 16 + l15;
            float bias = fc1_b[col];
#pragma unroll
            for (int r = 0; r < 4; ++r) {
                int row = wr * 32 + mi * 16 + g * 4 + r;  // C layout: row=(lane>>4)*4+reg
                h16[hidx(row, col)] = f2bf(acc[mi][ni][r] + bias);
            }
        }

    {   // y init = lout_b (uniform value: swizzle-invariant)
        ushort lbu = f2bf(lout_b[0]);
        ushort4 lv = { lbu, lbu, lbu, lbu };
#pragma unroll
        for (int i = 0; i < 8; ++i)
            reinterpret_cast<ushort4*>(y16)[i * 256 + tid] = lv;
    }
    __syncthreads();

    // ---- Phase 2: biLSTM, thread=(row,dir), 128 threads (2 waves), H=1 ----
    if (tid < 128) {
        int row = tid >> 1, dir = tid & 1;
        const float* wih = dir ? wih_b : wih_f;
        const float* whh = dir ? whh_b : whh_f;
        const float* bi  = dir ? bih_b : bih_f;
        const float* bh  = dir ? bhh_b : bhh_f;
        float wi0 = wih[0], wi1 = wih[1], wi2 = wih[2], wi3 = wih[3];
        float wh0 = whh[0], wh1 = whh[1], wh2 = whh[2], wh3 = whh[3];
        float c0 = bi[0] + bh[0], c1 = bi[1] + bh[1], c2 = bi[2] + bh[2], c3 = bi[3] + bh[3];
        float wsel = lout_w[dir];
        float hh = 0.f, cc = 0.f;
        for (int s = 0; s < 128; ++s) {
            int d = dir ? (127 - s) : s;
            float xv = bf2f(h16[hidx(row, d)]);
            float gi = fmaf(wi0, xv, fmaf(wh0, hh, c0));
            float gf = fmaf(wi1, xv, fmaf(wh1, hh, c1));
            float gg = fmaf(wi2, xv, fmaf(wh2, hh, c2));
            float go = fmaf(wi3, xv, fmaf(wh3, hh, c3));
            cc = sigm(gf) * cc + sigm(gi) * tanh_f(gg);
            hh = sigm(go) * tanh_f(cc);
            // fwd d=s, bwd d=127-s: never equal; same-wave lockstep orders the
            // cross-step RMWs to a shared cell -> race-free
            int yi = hidx(row, d);
            y16[yi] = f2bf(bf2f(y16[yi]) + wsel * hh);
        }
    }
    __syncthreads();

    // ---- Phase 3: emb1 = leaky(y @ w1^T + b1) via MFMA, then row-sum ----
    f32x4 accE[2][4];
#pragma unroll
    for (int mi = 0; mi < 2; ++mi)
#pragma unroll
        for (int ni = 0; ni < 4; ++ni) accE[mi][ni] = f32x4{0, 0, 0, 0};
    {
        const ushort* w1p = w1b + (size_t)(wc * 64 + l15) * 128 + g * 8;
#pragma unroll
        for (int k0 = 0; k0 < 128; k0 += 32) {
            int ro0 = wr * 32 + l15;
            int ro1 = ro0 + 16;
            short8 ya0 = *(const short8*)&y16[ro0 * 128 + ((k0 + g * 8) ^ ((ro0 & 7) << 3))];
            short8 ya1 = *(const short8*)&y16[ro1 * 128 + ((k0 + g * 8) ^ ((ro1 & 7) << 3))];
#pragma unroll
            for (int ni = 0; ni < 4; ++ni) {
                short8 wf = *(const short8*)(w1p + k0 + (size_t)ni * 16 * 128);
                accE[0][ni] = __builtin_amdgcn_mfma_f32_16x16x32_bf16(ya0, wf, accE[0][ni], 0, 0, 0);
                accE[1][ni] = __builtin_amdgcn_mfma_f32_16x16x32_bf16(ya1, wf, accE[1][ni], 0, 0, 0);
            }
        }
    }
    float* psum = (float*)smem;                           // 16 grp x 128 d fp32 = 8 KB (h16 dead)
#pragma unroll
    for (int mi = 0; mi < 2; ++mi)
#pragma unroll
        for (int ni = 0; ni < 4; ++ni) {
            int d1 = wc * 64 + ni * 16 + l15;
            float b1v = emb_b1[d1];
            float ssum = 0.f;
#pragma unroll
            for (int j = 0; j < 4; ++j) {
                float e = accE[mi][ni][j] + b1v;
                ssum += (e >= 0.f) ? e : 0.2f * e;
            }
            psum[((wr * 2 + mi) * 4 + g) * 128 + d1] = ssum;
        }
    __syncthreads();
    if (tid < 128) {
        float ssum = 0.f;
#pragma unroll
        for (int rg = 0; rg < 16; ++rg) ssum += psum[rg * 128 + tid];
        partials[(size_t)blk * 128 + tid] = ssum;
    }
}

// ---------------------------------------------------------------------------
// final: per-batch reduce of 8 partials, /T, then @ emb_w2^T + b2.
__global__ __launch_bounds__(128) void final_k(const float* __restrict__ partials,
                                               const float* __restrict__ w2t,
                                               const float* __restrict__ emb_b2,
                                               float* __restrict__ out) {
    __shared__ float S[128];
    int b = blockIdx.x, tid = threadIdx.x;
    float s = 0.f;
#pragma unroll
    for (int p = 0; p < 8; ++p) s += partials[(size_t)(b * 8 + p) * 128 + tid];
    S[tid] = s * (1.0f / 512.0f);
    __syncthreads();
    float acc = emb_b2[tid];
    for (int k = 0; k < 128; ++k) acc = fmaf(S[k], w2t[k * 128 + tid], acc);
    out[b * 128 + tid] = acc;
}

// ---------------------------------------------------------------------------
extern "C" void kernel_launch(void* const* d_in, const int* in_sizes, int n_in,
                              void* d_out, int out_size, void* d_ws, size_t ws_size,
                              hipStream_t stream) {
    const float* x      = (const float*)d_in[0];
    const float* fc1_w  = (const float*)d_in[1];
    const float* fc1_b  = (const float*)d_in[2];
    const float* wih_f  = (const float*)d_in[3];
    const float* whh_f  = (const float*)d_in[4];
    const float* bih_f  = (const float*)d_in[5];
    const float* bhh_f  = (const float*)d_in[6];
    const float* wih_b  = (const float*)d_in[7];
    const float* whh_b  = (const float*)d_in[8];
    const float* bih_b  = (const float*)d_in[9];
    const float* bhh_b  = (const float*)d_in[10];
    const float* lout_w = (const float*)d_in[11];
    const float* lout_b = (const float*)d_in[12];
    const float* emb_w1 = (const float*)d_in[13];
    const float* emb_b1 = (const float*)d_in[14];
    const float* emb_w2 = (const float*)d_in[15];
    const float* emb_b2 = (const float*)d_in[16];
    float* out = (float*)d_out;

    float*  partials = (float*)d_ws;               // 512*128 fp32 = 256 KB
    float*  w2t  = partials + 512 * 128;           // 16384 fp32 = 64 KB
    ushort* wb16 = (ushort*)(w2t + 16384);         // 131072 bf16 = 256 KB
    ushort* w1b  = wb16 + 131072;                  // 16384 bf16 = 32 KB

    prep_k<<<208, 256, 0, stream>>>(fc1_w, emb_w1, emb_w2, wb16, w1b, w2t);
    fused_k<<<512, 256, 0, stream>>>(x, wb16, fc1_b,
                                     wih_f, whh_f, bih_f, bhh_f,
                                     wih_b, whh_b, bih_b, bhh_b,
                                     lout_w, lout_b, w1b, emb_b1, partials);
    final_k<<<64, 128, 0, stream>>>(partials, w2t, emb_b2, out);
}